// Round 1
// baseline (178.883 us; speedup 1.0000x reference)
//
#include <hip/hip_runtime.h>
#include <hip/hip_bf16.h>
#include <stdint.h>

#define IN_F 512
#define OUT_F 512
#define BM 128
#define BN 128
#define BK 64
#define NTHREADS 256

typedef __attribute__((ext_vector_type(8))) short short8;
typedef __attribute__((ext_vector_type(4))) float floatx4;

__device__ __forceinline__ ushort f2bf(float f) {
  uint32_t u = __builtin_bit_cast(uint32_t, f);
  uint32_t r = u + 0x7fffu + ((u >> 16) & 1u);   // RNE bf16
  return (ushort)(r >> 16);
}

typedef const __attribute__((address_space(1))) uint32_t* gas1_u32;
typedef __attribute__((address_space(3))) uint32_t* gas3_u32;

__device__ __forceinline__ void gload_lds16(const void* g, void* l) {
  // per-lane global src, wave-uniform LDS base; HW writes base + lane*16
  __builtin_amdgcn_global_load_lds((gas1_u32)g, (gas3_u32)l, 16, 0, 0);
}

// ---------------------------------------------------------------------------
// Prep: build W_eff (512x512) in bf16, stored as per-(nt,kt) 128x64 tile
// images in the exact (swizzled) LDS layout the GEMM wants.
//   W_eff[O][C], O = og*128+o (out group r,i,j,k), C = cg*128+c.
// ---------------------------------------------------------------------------
__global__ void quat_prep_kernel(const float* __restrict__ wr, const float* __restrict__ wi,
                                 const float* __restrict__ wj, const float* __restrict__ wk,
                                 ushort* __restrict__ Bimg) {
  int idx = blockIdx.x * 256 + threadIdx.x;
  if (idx >= 512 * 512) return;
  int n = idx >> 9;        // O index
  int k = idx & 511;       // C index
  int og = n >> 7, o = n & 127, cg = k >> 7, c = k & 127;
  static const int   blkT[16] = {0,1,2,3, 1,0,3,2, 2,3,0,1, 3,2,1,0};
  static const float sgnT[16] = {1.f,-1.f,-1.f,-1.f, 1.f,1.f,1.f,-1.f,
                                 1.f,-1.f,1.f,1.f,   1.f,1.f,-1.f,1.f};
  int sel = og * 4 + cg;
  const float* Ws;
  switch (blkT[sel]) {
    case 0: Ws = wr; break;
    case 1: Ws = wi; break;
    case 2: Ws = wj; break;
    default: Ws = wk; break;
  }
  float v = sgnT[sel] * Ws[o * 128 + c];
  int nt = n >> 7, nl = n & 127;
  int kt = k >> 6, kl = k & 63;
  // tile image: row-major [nl][64] with XOR swizzle on k (element granularity)
  int dst = (nt * 8 + kt) * (BN * BK) + nl * BK + (kl ^ ((nl & 7) << 3));
  Bimg[dst] = f2bf(v);
}

// ---------------------------------------------------------------------------
// GEMM: out[M,512] = X[M,512] * W_eff^T  (+bias)
// 128x128 tile, BK=64, 4 waves (2Mx2N), 16x16x32 bf16 MFMA, double-buffered.
// ---------------------------------------------------------------------------
__global__ void __launch_bounds__(NTHREADS, 2)
quat_gemm_kernel(const float* __restrict__ X, const ushort* __restrict__ Bimg,
                 const float* __restrict__ bias, float* __restrict__ Out) {
  __shared__ __align__(16) ushort ldsA[2][BM * BK];
  __shared__ __align__(16) ushort ldsB[2][BN * BK];

  int nwg = gridDim.x;
  int bid = blockIdx.x;
  int wgid = bid;
  if ((nwg & 7) == 0) {                 // bijective XCD swizzle (nwg % 8 == 0)
    int per = nwg >> 3;
    wgid = (bid & 7) * per + (bid >> 3);
  }
  int mt = wgid >> 2;                   // N fastest: 4 siblings share X tile
  int nt = wgid & 3;

  int tid = threadIdx.x, lane = tid & 63, wid = tid >> 6;
  int wm = wid >> 1, wn = wid & 1;

  const float* Xblk = X + (size_t)mt * BM * IN_F;
  const ushort* Btiles = Bimg + nt * (8 * BN * BK);

  floatx4 acc[4][4];
#pragma unroll
  for (int m = 0; m < 4; ++m)
#pragma unroll
    for (int n = 0; n < 4; ++n) acc[m][n] = {0.f, 0.f, 0.f, 0.f};

  float4 av[8];
  const int r0 = tid >> 4;              // 0..15
  const int c4 = (tid & 15) * 4;        // 0..60, step 4

  auto loadA = [&](int kt) {
    const float* s = Xblk + (size_t)r0 * IN_F + kt * BK + c4;
#pragma unroll
    for (int p = 0; p < 8; ++p)
      av[p] = *reinterpret_cast<const float4*>(s + (size_t)p * 16 * IN_F);
  };

  auto writeA = [&](ushort* Ab) {
#pragma unroll
    for (int p = 0; p < 8; ++p) {
      int row = p * 16 + r0;
      ushort4 o4;
      o4.x = f2bf(av[p].x); o4.y = f2bf(av[p].y);
      o4.z = f2bf(av[p].z); o4.w = f2bf(av[p].w);
      *reinterpret_cast<ushort4*>(Ab + row * BK + (c4 ^ ((row & 7) << 3))) = o4;
    }
  };

  auto stageB = [&](int kt, ushort* Bb) {
    const ushort* t = Btiles + kt * (BN * BK);
#pragma unroll
    for (int i = 0; i < 4; ++i) {
      int chunk = wid * 4 + i;          // 16 chunks of 1024B
      gload_lds16(t + chunk * 512 + lane * 8, Bb + chunk * 512);
    }
  };

  auto compute = [&](const ushort* Ab, const ushort* Bb) {
    const int lrow = lane & 15;
#pragma unroll
    for (int kk = 0; kk < 2; ++kk) {
      int lk = kk * 32 + (lane >> 4) * 8;
      short8 af[4], bfr[4];
#pragma unroll
      for (int m = 0; m < 4; ++m) {
        int row = wm * 64 + m * 16 + lrow;
        af[m] = *reinterpret_cast<const short8*>(Ab + row * BK + (lk ^ ((row & 7) << 3)));
      }
#pragma unroll
      for (int n = 0; n < 4; ++n) {
        int row = wn * 64 + n * 16 + lrow;
        bfr[n] = *reinterpret_cast<const short8*>(Bb + row * BK + (lk ^ ((row & 7) << 3)));
      }
#pragma unroll
      for (int m = 0; m < 4; ++m)
#pragma unroll
        for (int n = 0; n < 4; ++n)
          acc[m][n] = __builtin_amdgcn_mfma_f32_16x16x32_bf16(af[m], bfr[n], acc[m][n], 0, 0, 0);
    }
  };

  // prologue: stage kt=0
  loadA(0);
  stageB(0, ldsB[0]);
  writeA(ldsA[0]);
  __syncthreads();                      // drains vmcnt+lgkm

#pragma unroll 1
  for (int kt = 0; kt < 8; ++kt) {
    int cur = kt & 1;
    if (kt < 7) {
      loadA(kt + 1);                    // issue global->reg loads (A)
      stageB(kt + 1, ldsB[cur ^ 1]);    // issue global_load_lds (B)
    }
    compute(ldsA[cur], ldsB[cur]);
    if (kt < 7) writeA(ldsA[cur ^ 1]);  // convert + ds_write next A
    __syncthreads();
  }

  // epilogue
  float* Ob = Out + (size_t)mt * BM * OUT_F + nt * BN;
  const float* bb = bias + nt * BN;
#pragma unroll
  for (int n = 0; n < 4; ++n) {
    int col = wn * 64 + n * 16 + (lane & 15);
    float bv = bb[col];
#pragma unroll
    for (int m = 0; m < 4; ++m) {
      int row0 = wm * 64 + m * 16 + (lane >> 4) * 4;
#pragma unroll
      for (int j = 0; j < 4; ++j)
        Ob[(size_t)(row0 + j) * OUT_F + col] = acc[m][n][j] + bv;
    }
  }
}

extern "C" void kernel_launch(void* const* d_in, const int* in_sizes, int n_in,
                              void* d_out, int out_size, void* d_ws, size_t ws_size,
                              hipStream_t stream) {
  const float* x    = (const float*)d_in[0];
  const float* wr   = (const float*)d_in[1];
  const float* wi   = (const float*)d_in[2];
  const float* wj   = (const float*)d_in[3];
  const float* wk   = (const float*)d_in[4];
  const float* bias = (const float*)d_in[5];
  float* out = (float*)d_out;
  ushort* Bimg = (ushort*)d_ws;         // 512 KB

  int M = in_sizes[0] / IN_F;           // 131072
  int mtiles = M / BM;                  // 1024
  int nwg = mtiles * (OUT_F / BN);      // 4096

  hipLaunchKernelGGL(quat_prep_kernel, dim3((512 * 512 + 255) / 256), dim3(256), 0, stream,
                     wr, wi, wj, wk, Bimg);
  hipLaunchKernelGGL(quat_gemm_kernel, dim3(nwg), dim3(NTHREADS), 0, stream,
                     x, Bimg, bias, out);
}